// Round 6
// baseline (909.062 us; speedup 1.0000x reference)
//
#include <hip/hip_runtime.h>

#define NE   32
#define DIN  256
#define DOUT 256
#define TM   32     // tokens per tile
#define TN   64     // outputs per tile

// Fully fused MoE: every block recomputes routing from the index array (16 KB,
// L2-broadcast), deterministically identical across blocks, then runs one
// 32x64 GEMM tile. W is register double-buffered with all prefetch issued
// AFTER the routing barriers (keeps W buffers' live ranges off the barrier
// region -- round 5's 256-VGPR spill lesson).
__global__ __launch_bounds__(256) void moe_fused_kernel(
    const float* __restrict__ x, const int* __restrict__ idx,
    const float* __restrict__ w, const float* __restrict__ bias,
    float* __restrict__ out)
{
    __shared__ int   cnt[NE];
    __shared__ int   wcnt[4];
    __shared__ int   sel[TM];
    __shared__ float xs[DIN][TM];   // 32 KB, [k][token]

    const int tid   = threadIdx.x;
    const int T     = blockIdx.x;       // global tile id
    const int obase = blockIdx.y * TN;

    // ---- A: load all 4096 indices, 4 int4 per thread (coalesced) ----
    const int4 c0 = *reinterpret_cast<const int4*>(idx + 0 * 1024 + tid * 4);
    const int4 c1 = *reinterpret_cast<const int4*>(idx + 1 * 1024 + tid * 4);
    const int4 c2 = *reinterpret_cast<const int4*>(idx + 2 * 1024 + tid * 4);
    const int4 c3 = *reinterpret_cast<const int4*>(idx + 3 * 1024 + tid * 4);

    // ---- B: histogram ----
    if (tid < NE) cnt[tid] = 0;
    __syncthreads();
    atomicAdd(&cnt[c0.x], 1); atomicAdd(&cnt[c0.y], 1); atomicAdd(&cnt[c0.z], 1); atomicAdd(&cnt[c0.w], 1);
    atomicAdd(&cnt[c1.x], 1); atomicAdd(&cnt[c1.y], 1); atomicAdd(&cnt[c1.z], 1); atomicAdd(&cnt[c1.w], 1);
    atomicAdd(&cnt[c2.x], 1); atomicAdd(&cnt[c2.y], 1); atomicAdd(&cnt[c2.z], 1); atomicAdd(&cnt[c2.w], 1);
    atomicAdd(&cnt[c3.x], 1); atomicAdd(&cnt[c3.y], 1); atomicAdd(&cnt[c3.z], 1); atomicAdd(&cnt[c3.w], 1);
    __syncthreads();

    // ---- C: tile -> (expert, selection window) ; replicated scan ----
    int e = -1, sel_lo = 0, m = 0;
    {
        int tp = 0;
        for (int ee = 0; ee < NE; ++ee) {
            const int ce = cnt[ee];
            const int nt = (ce + TM - 1) >> 5;
            if (e < 0 && T < tp + nt) { e = ee; sel_lo = (T - tp) * TM; m = min(TM, ce - sel_lo); }
            tp += nt;
        }
    }
    if (e < 0) return;   // block-uniform exit

    // ---- D: ballot-based stable selection of this tile's tokens ----
    const int lane = tid & 63;
    const int wid  = tid >> 6;
    const unsigned long long lt = (1ull << lane) - 1ull;
    int running = 0;

#define SEL_ROUND(cr, R)                                                                             \
    {                                                                                                \
        const unsigned long long m0 = __ballot((cr).x == e);                                         \
        const unsigned long long m1 = __ballot((cr).y == e);                                         \
        const unsigned long long m2 = __ballot((cr).z == e);                                         \
        const unsigned long long m3 = __ballot((cr).w == e);                                         \
        const int p0 = __popcll(m0), p1 = __popcll(m1), p2 = __popcll(m2), p3 = __popcll(m3);        \
        if (lane == 0) wcnt[wid] = p0 + p1 + p2 + p3;                                                \
        __syncthreads();                                                                             \
        int wb_ = running;                                                                           \
        if (wid > 0) wb_ += wcnt[0];                                                                 \
        if (wid > 1) wb_ += wcnt[1];                                                                 \
        if (wid > 2) wb_ += wcnt[2];                                                                 \
        const int b0 = wb_, b1 = b0 + p0, b2 = b1 + p1, b3 = b2 + p2;                                \
        const int tokbase = (R) * 1024 + tid * 4;                                                    \
        if ((cr).x == e) { const int o = b0 + __popcll(m0 & lt) - sel_lo; if ((unsigned)o < (unsigned)TM) sel[o] = tokbase + 0; } \
        if ((cr).y == e) { const int o = b1 + __popcll(m1 & lt) - sel_lo; if ((unsigned)o < (unsigned)TM) sel[o] = tokbase + 1; } \
        if ((cr).z == e) { const int o = b2 + __popcll(m2 & lt) - sel_lo; if ((unsigned)o < (unsigned)TM) sel[o] = tokbase + 2; } \
        if ((cr).w == e) { const int o = b3 + __popcll(m3 & lt) - sel_lo; if ((unsigned)o < (unsigned)TM) sel[o] = tokbase + 3; } \
        running += wcnt[0] + wcnt[1] + wcnt[2] + wcnt[3];                                            \
        __syncthreads();                                                                             \
    }

    SEL_ROUND(c0, 0)
    if (running < sel_lo + m) SEL_ROUND(c1, 1)
    if (running < sel_lo + m) SEL_ROUND(c2, 2)
    if (running < sel_lo + m) SEL_ROUND(c3, 3)
#undef SEL_ROUND

    // ---- E: stage x tile (transposed) into LDS ----
    {
        const int t = tid & 31;        // token slot
        const int g = tid >> 5;        // k-group
        const int trow = sel[min(t, m - 1)];
        const float* xrow = x + (size_t)trow * DIN;
#pragma unroll
        for (int j = 0; j < 8; ++j) {
            const int k0 = (g * 8 + j) * 4;
            const float4 vv = *reinterpret_cast<const float4*>(xrow + k0);
            xs[k0 + 0][t] = vv.x;
            xs[k0 + 1][t] = vv.y;
            xs[k0 + 2][t] = vv.z;
            xs[k0 + 3][t] = vv.w;
        }
    }
    __syncthreads();

    // ---- F: software-pipelined main loop (16 chunks x 16 ksteps) ----
    // All W-buffer liveness starts AFTER the last barrier. Two named buffers,
    // modulo-2 rotation, fully static indexing. Load of chunk c+2 is issued
    // right after chunk c is consumed -> load-to-use distance ~128 FMAs.
    const int og = tid & 31;   // 32 x 2 = 64 outputs
    const int tg = tid >> 5;   //  8 x 4 = 32 tokens
    const float* wp = w + (size_t)e * DIN * DOUT + obase + og * 2;

#define LOAD_CHUNK(buf, cc)                                                          \
    _Pragma("unroll")                                                                \
    for (int j = 0; j < 16; ++j)                                                     \
        buf[j] = *reinterpret_cast<const float2*>(wp + (size_t)((cc) * 16 + j) * DOUT);

#define FMA_CHUNK(buf, cc)                                                           \
    _Pragma("unroll")                                                                \
    for (int j = 0; j < 16; ++j) {                                                   \
        const float4 xv = *reinterpret_cast<const float4*>(&xs[(cc) * 16 + j][tg * 4]);\
        acc[0][0] = fmaf(xv.x, buf[j].x, acc[0][0]);                                 \
        acc[0][1] = fmaf(xv.x, buf[j].y, acc[0][1]);                                 \
        acc[1][0] = fmaf(xv.y, buf[j].x, acc[1][0]);                                 \
        acc[1][1] = fmaf(xv.y, buf[j].y, acc[1][1]);                                 \
        acc[2][0] = fmaf(xv.z, buf[j].x, acc[2][0]);                                 \
        acc[2][1] = fmaf(xv.z, buf[j].y, acc[2][1]);                                 \
        acc[3][0] = fmaf(xv.w, buf[j].x, acc[3][0]);                                 \
        acc[3][1] = fmaf(xv.w, buf[j].y, acc[3][1]);                                 \
    }

    float2 wA[16], wB[16];
    float acc[4][2] = {};
    LOAD_CHUNK(wA, 0)
    LOAD_CHUNK(wB, 1)
#pragma unroll
    for (int c = 0; c < 16; ++c) {
        if ((c & 1) == 0) {
            FMA_CHUNK(wA, c)
            if (c + 2 < 16) LOAD_CHUNK(wA, c + 2)
        } else {
            FMA_CHUNK(wB, c)
            if (c + 2 < 16) LOAD_CHUNK(wB, c + 2)
        }
    }
#undef LOAD_CHUNK
#undef FMA_CHUNK

    // ---- G: epilogue ----
    const float2 bv = *reinterpret_cast<const float2*>(bias + (size_t)e * DOUT + obase + og * 2);
#pragma unroll
    for (int tt = 0; tt < 4; ++tt) {
        const int tl = tg * 4 + tt;
        if (tl < m) {
            const int row = sel[tl];
            float2 o;
            o.x = acc[tt][0] + bv.x;
            o.y = acc[tt][1] + bv.y;
            *reinterpret_cast<float2*>(out + (size_t)row * DOUT + obase + og * 2) = o;
        }
    }
}

extern "C" void kernel_launch(void* const* d_in, const int* in_sizes, int n_in,
                              void* d_out, int out_size, void* d_ws, size_t ws_size,
                              hipStream_t stream) {
    const float* x      = (const float*)d_in[0];
    const int*   index  = (const int*)d_in[1];
    const float* weight = (const float*)d_in[2];
    const float* bias   = (const float*)d_in[3];
    float* out = (float*)d_out;

    // worst case tiles: 128 full + 31 partial = 159
    dim3 grid(160, 4);
    moe_fused_kernel<<<grid, 256, 0, stream>>>(x, index, weight, bias, out);
}

// Round 7
// 38.448 us; speedup vs baseline: 23.6442x; 23.6442x over previous
//
#include <hip/hip_runtime.h>

#define NE   32
#define DIN  256
#define DOUT 256
#define TM   32     // tokens per tile
#define TN   64     // outputs per tile

// Fully fused MoE: every block recomputes routing from the index array (16 KB,
// L2-broadcast), deterministically identical across blocks, then runs one
// 32x64 GEMM tile. W is register double-buffered; the pipeline loop is
// #pragma unroll 1 -- R5/R6 showed that unrolling it merges buffer liveness
// across chunks (256 VGPR, scratch spill, 25x slowdown).
__global__ __launch_bounds__(256) void moe_fused_kernel(
    const float* __restrict__ x, const int* __restrict__ idx,
    const float* __restrict__ w, const float* __restrict__ bias,
    float* __restrict__ out)
{
    __shared__ int   cnt[NE];
    __shared__ int   wcnt[4];
    __shared__ int   sel[TM];
    __shared__ float xs[DIN][TM];   // 32 KB, [k][token]

    const int tid = threadIdx.x;
    // XCD swizzle: tiles are expert-sorted; dispatch assigns xcd = bx % 8.
    // Map so each XCD gets 20 CONSECUTIVE tiles (~4 experts, ~1 MB W -> L2-resident).
    const int T     = (blockIdx.x & 7) * 20 + (blockIdx.x >> 3);
    const int obase = blockIdx.y * TN;

    // ---- A: load all 4096 indices, 4 int4 per thread (coalesced) ----
    const int4 c0 = *reinterpret_cast<const int4*>(idx + 0 * 1024 + tid * 4);
    const int4 c1 = *reinterpret_cast<const int4*>(idx + 1 * 1024 + tid * 4);
    const int4 c2 = *reinterpret_cast<const int4*>(idx + 2 * 1024 + tid * 4);
    const int4 c3 = *reinterpret_cast<const int4*>(idx + 3 * 1024 + tid * 4);

    // ---- B: histogram ----
    if (tid < NE) cnt[tid] = 0;
    __syncthreads();
    atomicAdd(&cnt[c0.x], 1); atomicAdd(&cnt[c0.y], 1); atomicAdd(&cnt[c0.z], 1); atomicAdd(&cnt[c0.w], 1);
    atomicAdd(&cnt[c1.x], 1); atomicAdd(&cnt[c1.y], 1); atomicAdd(&cnt[c1.z], 1); atomicAdd(&cnt[c1.w], 1);
    atomicAdd(&cnt[c2.x], 1); atomicAdd(&cnt[c2.y], 1); atomicAdd(&cnt[c2.z], 1); atomicAdd(&cnt[c2.w], 1);
    atomicAdd(&cnt[c3.x], 1); atomicAdd(&cnt[c3.y], 1); atomicAdd(&cnt[c3.z], 1); atomicAdd(&cnt[c3.w], 1);
    __syncthreads();

    // ---- C: tile -> (expert, selection window) ; replicated scan ----
    int e = -1, sel_lo = 0, m = 0;
    {
        int tp = 0;
        for (int ee = 0; ee < NE; ++ee) {
            const int ce = cnt[ee];
            const int nt = (ce + TM - 1) >> 5;
            if (e < 0 && T < tp + nt) { e = ee; sel_lo = (T - tp) * TM; m = min(TM, ce - sel_lo); }
            tp += nt;
        }
    }
    if (e < 0) return;   // block-uniform exit

    // ---- D: ballot-based stable selection of this tile's tokens ----
    const int lane = tid & 63;
    const int wid  = tid >> 6;
    const unsigned long long lt = (1ull << lane) - 1ull;
    int running = 0;

#define SEL_ROUND(cr, R)                                                                             \
    {                                                                                                \
        const unsigned long long m0 = __ballot((cr).x == e);                                         \
        const unsigned long long m1 = __ballot((cr).y == e);                                         \
        const unsigned long long m2 = __ballot((cr).z == e);                                         \
        const unsigned long long m3 = __ballot((cr).w == e);                                         \
        const int p0 = __popcll(m0), p1 = __popcll(m1), p2 = __popcll(m2), p3 = __popcll(m3);        \
        if (lane == 0) wcnt[wid] = p0 + p1 + p2 + p3;                                                \
        __syncthreads();                                                                             \
        int wb_ = running;                                                                           \
        if (wid > 0) wb_ += wcnt[0];                                                                 \
        if (wid > 1) wb_ += wcnt[1];                                                                 \
        if (wid > 2) wb_ += wcnt[2];                                                                 \
        const int b0 = wb_, b1 = b0 + p0, b2 = b1 + p1, b3 = b2 + p2;                                \
        const int tokbase = (R) * 1024 + tid * 4;                                                    \
        if ((cr).x == e) { const int o = b0 + __popcll(m0 & lt) - sel_lo; if ((unsigned)o < (unsigned)TM) sel[o] = tokbase + 0; } \
        if ((cr).y == e) { const int o = b1 + __popcll(m1 & lt) - sel_lo; if ((unsigned)o < (unsigned)TM) sel[o] = tokbase + 1; } \
        if ((cr).z == e) { const int o = b2 + __popcll(m2 & lt) - sel_lo; if ((unsigned)o < (unsigned)TM) sel[o] = tokbase + 2; } \
        if ((cr).w == e) { const int o = b3 + __popcll(m3 & lt) - sel_lo; if ((unsigned)o < (unsigned)TM) sel[o] = tokbase + 3; } \
        running += wcnt[0] + wcnt[1] + wcnt[2] + wcnt[3];                                            \
        __syncthreads();                                                                             \
    }

    SEL_ROUND(c0, 0)
    if (running < sel_lo + m) SEL_ROUND(c1, 1)
    if (running < sel_lo + m) SEL_ROUND(c2, 2)
    if (running < sel_lo + m) SEL_ROUND(c3, 3)
#undef SEL_ROUND

    // ---- E: stage x tile (transposed) into LDS ----
    {
        const int t = tid & 31;        // token slot
        const int g = tid >> 5;        // k-group
        const int trow = sel[min(t, m - 1)];
        const float* xrow = x + (size_t)trow * DIN;
#pragma unroll
        for (int j = 0; j < 8; ++j) {
            const int k0 = (g * 8 + j) * 4;
            const float4 vv = *reinterpret_cast<const float4*>(xrow + k0);
            xs[k0 + 0][t] = vv.x;
            xs[k0 + 1][t] = vv.y;
            xs[k0 + 2][t] = vv.z;
            xs[k0 + 3][t] = vv.w;
        }
    }
    __syncthreads();

    // ---- F: register double-buffered main loop ----
    // 16 chunks of 16 k-steps, processed in 8 NON-UNROLLED pair-iterations.
    // Liveness is structurally capped at wA+wB (64 VGPR): the load that
    // overwrites a buffer cannot move above the FMA block reading it (WAR),
    // and `#pragma unroll 1` blocks cross-iteration hoisting.
    const int og = tid & 31;   // 32 x 2 = 64 outputs
    const int tg = tid >> 5;   //  8 x 4 = 32 tokens
    const float* wp = w + (size_t)e * DIN * DOUT + obase + og * 2;

#define LOAD_CHUNK(buf, cc)                                                            \
    _Pragma("unroll")                                                                  \
    for (int j = 0; j < 16; ++j)                                                       \
        buf[j] = *reinterpret_cast<const float2*>(wp + (size_t)((cc) * 16 + j) * DOUT);

#define FMA_CHUNK(buf, cc)                                                             \
    _Pragma("unroll")                                                                  \
    for (int j = 0; j < 16; ++j) {                                                     \
        const float4 xv = *reinterpret_cast<const float4*>(&xs[(cc) * 16 + j][tg * 4]);\
        acc[0][0] = fmaf(xv.x, buf[j].x, acc[0][0]);                                   \
        acc[0][1] = fmaf(xv.x, buf[j].y, acc[0][1]);                                   \
        acc[1][0] = fmaf(xv.y, buf[j].x, acc[1][0]);                                   \
        acc[1][1] = fmaf(xv.y, buf[j].y, acc[1][1]);                                   \
        acc[2][0] = fmaf(xv.z, buf[j].x, acc[2][0]);                                   \
        acc[2][1] = fmaf(xv.z, buf[j].y, acc[2][1]);                                   \
        acc[3][0] = fmaf(xv.w, buf[j].x, acc[3][0]);                                   \
        acc[3][1] = fmaf(xv.w, buf[j].y, acc[3][1]);                                   \
    }

    float2 wA[16], wB[16];
    float acc[4][2] = {};
    LOAD_CHUNK(wA, 0)
#pragma unroll 1
    for (int c = 0; c < 8; ++c) {
        LOAD_CHUNK(wB, 2 * c + 1)     // issue B-loads; covered by FMA on wA
        FMA_CHUNK(wA, 2 * c)
        if (c < 7) LOAD_CHUNK(wA, 2 * c + 2)   // issue next A; covered by FMA on wB
        FMA_CHUNK(wB, 2 * c + 1)
    }
#undef LOAD_CHUNK
#undef FMA_CHUNK

    // ---- G: epilogue ----
    const float2 bv = *reinterpret_cast<const float2*>(bias + (size_t)e * DOUT + obase + og * 2);
#pragma unroll
    for (int tt = 0; tt < 4; ++tt) {
        const int tl = tg * 4 + tt;
        if (tl < m) {
            const int row = sel[tl];
            float2 o;
            o.x = acc[tt][0] + bv.x;
            o.y = acc[tt][1] + bv.y;
            *reinterpret_cast<float2*>(out + (size_t)row * DOUT + obase + og * 2) = o;
        }
    }
}

extern "C" void kernel_launch(void* const* d_in, const int* in_sizes, int n_in,
                              void* d_out, int out_size, void* d_ws, size_t ws_size,
                              hipStream_t stream) {
    const float* x      = (const float*)d_in[0];
    const int*   index  = (const int*)d_in[1];
    const float* weight = (const float*)d_in[2];
    const float* bias   = (const float*)d_in[3];
    float* out = (float*)d_out;

    // worst case tiles: 128 full + 31 partial = 159 (grid 160 = 8 XCDs x 20)
    dim3 grid(160, 4);
    moe_fused_kernel<<<grid, 256, 0, stream>>>(x, index, weight, bias, out);
}

// Round 8
// 34.062 us; speedup vs baseline: 26.6887x; 1.1288x over previous
//
#include <hip/hip_runtime.h>

#define NE   32
#define DIN  256
#define DOUT 256
#define TN   32     // output cols per block
#define CT   64     // tokens per chunk

// W-stationary MoE: one block per (expert, 32-col slice). Block stages its
// 256x32 W panel into LDS ONCE (read from HBM exactly once chip-wide), then
// streams the expert's tokens through in 64-token chunks. The k-loop touches
// only LDS -- no global loads in the inner loop, so no exposed HBM/L2 latency
// (R4-R7 lesson: that latency, unhidden at low occupancy, was the 40 us).
__global__ __launch_bounds__(256) void moe_expert_kernel(
    const float* __restrict__ x, const int* __restrict__ idx,
    const float* __restrict__ w, const float* __restrict__ bias,
    float* __restrict__ out)
{
    __shared__ float wsm[DIN][TN];    // 32 KB  [k][col]
    __shared__ float xs[DIN][CT];     // 64 KB  [k][token]
    __shared__ int   toklist[4096];   // 16 KB  (worst case: all tokens on one expert)
    __shared__ int   scnt;

    const int tid   = threadIdx.x;
    const int e     = blockIdx.x >> 3;   // expert
    const int cb    = blockIdx.x & 7;    // col slice == XCD id (L2 locality)
    const int obase = cb * TN;

    if (tid == 0) scnt = 0;
    __syncthreads();

    // ---- collect this expert's tokens (16 KB scan, L2-broadcast).
    // Append order is nondeterministic, but each token's output is computed
    // identically regardless of list position -> bitwise-deterministic output.
#pragma unroll
    for (int r = 0; r < 4; ++r) {
        const int base = r * 1024 + tid * 4;
        const int4 v = *reinterpret_cast<const int4*>(idx + base);
        if (v.x == e) toklist[atomicAdd(&scnt, 1)] = base + 0;
        if (v.y == e) toklist[atomicAdd(&scnt, 1)] = base + 1;
        if (v.z == e) toklist[atomicAdd(&scnt, 1)] = base + 2;
        if (v.w == e) toklist[atomicAdd(&scnt, 1)] = base + 3;
    }

    // ---- stage W panel (32 KB) into LDS; overlaps the collect phase ----
    {
        const int kr = tid >> 3;          // k row within pass: 0..31
        const int c4 = (tid & 7) * 4;     // col quad: 0,4,...,28
        const float* wpe = w + (size_t)e * DIN * DOUT + obase;
#pragma unroll
        for (int p = 0; p < 8; ++p) {
            const int k = p * 32 + kr;
            const float4 v = *reinterpret_cast<const float4*>(wpe + (size_t)k * DOUT + c4);
            wsm[k][c4 + 0] = v.x; wsm[k][c4 + 1] = v.y;
            wsm[k][c4 + 2] = v.z; wsm[k][c4 + 3] = v.w;
        }
    }
    __syncthreads();
    const int ce = scnt;
    if (ce == 0) return;   // block-uniform exit

    const int og = tid & 15;   // 16 x 2 = 32 outputs
    const int tg = tid >> 4;   // 16 x 4 = 64 tokens
    const float2 bv = *reinterpret_cast<const float2*>(bias + (size_t)e * DOUT + obase + og * 2);

    for (int t0 = 0; t0 < ce; t0 += CT) {
        if (t0) __syncthreads();   // xs overwrite guard vs previous chunk's reads

        // ---- gather 64 x rows into xs (transposed) ----
        {
            const int slot = tid & 63;            // token slot
            const int kq   = (tid >> 6) * 64;     // k quarter
            const int tok  = toklist[min(t0 + slot, ce - 1)];
            const float* xr = x + (size_t)tok * DIN;
#pragma unroll
            for (int j = 0; j < 16; ++j) {
                const int k0 = kq + j * 4;
                const float4 v = *reinterpret_cast<const float4*>(xr + k0);
                xs[k0 + 0][slot] = v.x; xs[k0 + 1][slot] = v.y;
                xs[k0 + 2][slot] = v.z; xs[k0 + 3][slot] = v.w;
            }
        }
        __syncthreads();

        // ---- LDS-only k-loop: 4 tokens x 2 outs per thread ----
        float acc[4][2] = {};
#pragma unroll 8
        for (int k = 0; k < DIN; ++k) {
            const float2 wv = *reinterpret_cast<const float2*>(&wsm[k][og * 2]);
            const float4 xv = *reinterpret_cast<const float4*>(&xs[k][tg * 4]);
            acc[0][0] = fmaf(xv.x, wv.x, acc[0][0]);
            acc[0][1] = fmaf(xv.x, wv.y, acc[0][1]);
            acc[1][0] = fmaf(xv.y, wv.x, acc[1][0]);
            acc[1][1] = fmaf(xv.y, wv.y, acc[1][1]);
            acc[2][0] = fmaf(xv.z, wv.x, acc[2][0]);
            acc[2][1] = fmaf(xv.z, wv.y, acc[2][1]);
            acc[3][0] = fmaf(xv.w, wv.x, acc[3][0]);
            acc[3][1] = fmaf(xv.w, wv.y, acc[3][1]);
        }

        // ---- epilogue: bias + scatter ----
#pragma unroll
        for (int tt = 0; tt < 4; ++tt) {
            const int sl = t0 + tg * 4 + tt;
            if (sl < ce) {
                const int row = toklist[sl];
                float2 o;
                o.x = acc[tt][0] + bv.x;
                o.y = acc[tt][1] + bv.y;
                *reinterpret_cast<float2*>(out + (size_t)row * DOUT + obase + og * 2) = o;
            }
        }
    }
}

extern "C" void kernel_launch(void* const* d_in, const int* in_sizes, int n_in,
                              void* d_out, int out_size, void* d_ws, size_t ws_size,
                              hipStream_t stream) {
    const float* x      = (const float*)d_in[0];
    const int*   index  = (const int*)d_in[1];
    const float* weight = (const float*)d_in[2];
    const float* bias   = (const float*)d_in[3];
    float* out = (float*)d_out;

    // 32 experts x 8 col-slices = 256 blocks = 1 per CU
    moe_expert_kernel<<<NE * 8, 256, 0, stream>>>(x, index, weight, bias, out);
}

// Round 10
// 17.545 us; speedup vs baseline: 51.8134x; 1.9414x over previous
//
#include <hip/hip_runtime.h>

#define NE   32
#define DIN  256
#define DOUT 256
#define TN   32     // output cols per block
#define CT   64     // tokens per chunk
#define XSTR 264    // u16 stride (256 + 8 pad) = 528 B = 132 dw (== 4 mod 32 -> banks spread)

typedef __attribute__((ext_vector_type(8))) short short8v;   // 8 bf16 = 4 VGPR (guide §3)
typedef __attribute__((ext_vector_type(4))) float float4v;   // MFMA accumulator

__device__ __forceinline__ unsigned short f2bf(float f) {
    // fp32 -> bf16 round-to-nearest-even (inputs finite)
    unsigned u = __float_as_uint(f);
    return (unsigned short)((u + 0x7FFFu + ((u >> 16) & 1u)) >> 16);
}

// MFMA MoE: block = (expert, 32-col slice). W panel converted to bf16 and held
// transposed in LDS (B-frag reads = contiguous-8 k per lane); expert's tokens
// streamed in 64-token chunks through xls. k-loop: 3 ds_read_b128 + 2 MFMA per
// 32-k slice per wave. R9's failure was NOT the MFMA layout: the COLLECT macro
// declared `int base` shadowing the caller's `base` token id, so toklist was
// filled with scnt offsets. Fixed by renaming (sbase / tb).
__global__ __launch_bounds__(256) void moe_mfma_kernel(
    const float* __restrict__ x, const int* __restrict__ idx,
    const float* __restrict__ w, const float* __restrict__ bias,
    float* __restrict__ out)
{
    __shared__ unsigned short xls[CT * XSTR];   // 33792 B  [token][k] bf16
    __shared__ unsigned short wls[TN * XSTR];   // 16896 B  [col][k]   bf16 (transposed)
    __shared__ int toklist[4096];               // 16 KB
    __shared__ int scnt;

    const int tid  = threadIdx.x;
    const int e    = blockIdx.x & 31;    // expert; XCD = blockIdx.x % 8 = e % 8
    const int cb   = blockIdx.x >> 5;    // col slice
    const int obase = cb * TN;
    const int lane = tid & 63;
    const int wid  = tid >> 6;

    if (tid == 0) scnt = 0;
    __syncthreads();

    // ---- collect this expert's tokens; ballot-aggregated (4 atomics/wave).
    // List order is nondeterministic but per-token math is position-independent
    // -> bitwise-deterministic output.
    const unsigned long long lt = (1ull << lane) - 1ull;
#define COLLECT(val, tokid)                                                   \
    {                                                                         \
        const unsigned long long mk = __ballot((val) == e);                   \
        if (mk) {                                                             \
            const int leader = __ffsll((unsigned long long)mk) - 1;           \
            int sbase = 0;                                                    \
            if (lane == leader) sbase = atomicAdd(&scnt, __popcll(mk));       \
            sbase = __shfl(sbase, leader);                                    \
            if ((val) == e) toklist[sbase + __popcll(mk & lt)] = (tokid);     \
        }                                                                     \
    }
#pragma unroll
    for (int r = 0; r < 4; ++r) {
        const int tb = r * 1024 + tid * 4;
        const int4 v = *reinterpret_cast<const int4*>(idx + tb);
        COLLECT(v.x, tb + 0)
        COLLECT(v.y, tb + 1)
        COLLECT(v.z, tb + 2)
        COLLECT(v.w, tb + 3)
    }
#undef COLLECT

    // ---- stage W panel -> bf16, transposed [col][k]; thread t handles k = t ----
    {
        const float* wr = w + (size_t)e * DIN * DOUT + (size_t)tid * DOUT + obase;
#pragma unroll
        for (int j = 0; j < 8; ++j) {
            const float4 v = *reinterpret_cast<const float4*>(wr + j * 4);
            wls[(j * 4 + 0) * XSTR + tid] = f2bf(v.x);
            wls[(j * 4 + 1) * XSTR + tid] = f2bf(v.y);
            wls[(j * 4 + 2) * XSTR + tid] = f2bf(v.z);
            wls[(j * 4 + 3) * XSTR + tid] = f2bf(v.w);
        }
    }
    __syncthreads();
    const int ce = scnt;
    if (ce == 0) return;   // block-uniform

    // fragment lane roles (16x16x32 bf16):
    //   A: row = lane&15, k = (lane>>4)*8 + i   (contiguous 8 -> one b128)
    //   B: col = lane&15, k = (lane>>4)*8 + i
    //   C/D: col = lane&15, row = (lane>>4)*4 + reg   [m89-verified]
    const int a15 = lane & 15;
    const int kg  = lane >> 4;
    const float bv0 = bias[(size_t)e * DOUT + obase + a15];
    const float bv1 = bias[(size_t)e * DOUT + obase + 16 + a15];

    for (int t0 = 0; t0 < ce; t0 += CT) {
        if (t0) __syncthreads();   // xls overwrite guard

        // ---- gather 64 token rows -> bf16 -> xls[tok][k] ----
        {
            const int slot = tid & 63;            // token slot (lane-major: banks spread)
            const int kq   = (tid >> 6) * 64;     // k-quarter per wave
            const int tok  = toklist[min(t0 + slot, ce - 1)];
            const float* xr = x + (size_t)tok * DIN + kq;
            unsigned short* dst = &xls[slot * XSTR + kq];
#pragma unroll
            for (int j = 0; j < 16; ++j) {
                const float4 v = *reinterpret_cast<const float4*>(xr + j * 4);
                uint2 p;
                p.x = (unsigned)f2bf(v.x) | ((unsigned)f2bf(v.y) << 16);
                p.y = (unsigned)f2bf(v.z) | ((unsigned)f2bf(v.w) << 16);
                *reinterpret_cast<uint2*>(dst + j * 4) = p;
            }
        }
        __syncthreads();

        // ---- MFMA k-loop: wave owns 16 tokens x 32 cols ----
        const unsigned short* ax  = &xls[(wid * 16 + a15) * XSTR];
        const unsigned short* bw0 = &wls[a15 * XSTR];
        const unsigned short* bw1 = &wls[(16 + a15) * XSTR];
        float4v acc0 = {0.f, 0.f, 0.f, 0.f};
        float4v acc1 = {0.f, 0.f, 0.f, 0.f};
#pragma unroll
        for (int kk = 0; kk < 8; ++kk) {
            const int kb = kk * 32 + kg * 8;
            const short8v a  = *reinterpret_cast<const short8v*>(ax + kb);
            const short8v b0 = *reinterpret_cast<const short8v*>(bw0 + kb);
            const short8v b1 = *reinterpret_cast<const short8v*>(bw1 + kb);
            acc0 = __builtin_amdgcn_mfma_f32_16x16x32_bf16(a, b0, acc0, 0, 0, 0);
            acc1 = __builtin_amdgcn_mfma_f32_16x16x32_bf16(a, b1, acc1, 0, 0, 0);
        }

        // ---- store: row = t0 + wid*16 + kg*4 + r, cols obase+a15 / +16+a15 ----
#pragma unroll
        for (int r = 0; r < 4; ++r) {
            const int sl = t0 + wid * 16 + kg * 4 + r;
            if (sl < ce) {
                const int row = toklist[sl];
                float* op = out + (size_t)row * DOUT + obase;
                op[a15]      = acc0[r] + bv0;
                op[16 + a15] = acc1[r] + bv1;
            }
        }
    }
}

extern "C" void kernel_launch(void* const* d_in, const int* in_sizes, int n_in,
                              void* d_out, int out_size, void* d_ws, size_t ws_size,
                              hipStream_t stream) {
    const float* x      = (const float*)d_in[0];
    const int*   index  = (const int*)d_in[1];
    const float* weight = (const float*)d_in[2];
    const float* bias   = (const float*)d_in[3];
    float* out = (float*)d_out;

    // 32 experts x 8 col-slices = 256 blocks = 1 per CU; bx = cb*32 + e -> XCD = e%8
    moe_mfma_kernel<<<NE * 8, 256, 0, stream>>>(x, index, weight, bias, out);
}

// Round 11
// 15.961 us; speedup vs baseline: 56.9551x; 1.0992x over previous
//
#include <hip/hip_runtime.h>

#define NE   32
#define DIN  256
#define DOUT 256
#define TN   32     // output cols per block
#define CT   64     // tokens per chunk
#define XSTR 264    // u16 stride (256 + 8 pad) = 528 B -> lane-row reads spread banks

typedef __attribute__((ext_vector_type(8))) short short8v;   // 8 bf16 = 4 VGPR
typedef __attribute__((ext_vector_type(4))) float float4v;   // MFMA accumulator

__device__ __forceinline__ unsigned short f2bf(float f) {
    // fp32 -> bf16 round-to-nearest-even (inputs finite)
    unsigned u = __float_as_uint(f);
    return (unsigned short)((u + 0x7FFFu + ((u >> 16) & 1u)) >> 16);
}

// MFMA MoE, token-split: block = (token-half, expert, 32-col slice), grid 512
// = 2 blocks/CU (LDS 59 KB). Collect is a deterministic ballot-scan (no LDS
// atomics; toklist is a pure function of idx, so both token-halves of an
// expert compute identical lists and partition the chunks disjointly).
// bx % 8 == e % 8 keeps all 16 blocks of an expert on one XCD -> x rows hit L2.
__global__ __launch_bounds__(256) void moe_mfma_kernel(
    const float* __restrict__ x, const int* __restrict__ idx,
    const float* __restrict__ w, const float* __restrict__ bias,
    float* __restrict__ out)
{
    __shared__ unsigned short xls[CT * XSTR];   // 33792 B  [token][k] bf16
    __shared__ unsigned short wls[TN * XSTR];   // 16896 B  [col][k]   bf16 (transposed)
    __shared__ unsigned short toklist[4096];    //  8192 B  token ids (u16)
    __shared__ int wcnt[4];

    const int tid   = threadIdx.x;
    const int e     = blockIdx.x & 31;          // expert; XCD = bx%8 = e%8
    const int cb    = (blockIdx.x >> 5) & 7;    // col slice
    const int half  = blockIdx.x >> 8;          // token-half
    const int obase = cb * TN;
    const int lane  = tid & 63;
    const int wid   = tid >> 6;
    const unsigned long long lt = (1ull << lane) - 1ull;

    // ---- collect: deterministic ballot-scan (position = ordinal in token order) ----
    int running = 0;
#pragma unroll
    for (int r = 0; r < 4; ++r) {
        const int tb = r * 1024 + tid * 4;
        const int4 v = *reinterpret_cast<const int4*>(idx + tb);
        const unsigned long long m0 = __ballot(v.x == e);
        const unsigned long long m1 = __ballot(v.y == e);
        const unsigned long long m2 = __ballot(v.z == e);
        const unsigned long long m3 = __ballot(v.w == e);
        const int p0 = __popcll(m0), p1 = __popcll(m1), p2 = __popcll(m2), p3 = __popcll(m3);
        if (lane == 0) wcnt[wid] = p0 + p1 + p2 + p3;
        __syncthreads();
        int wb = running;
        if (wid > 0) wb += wcnt[0];
        if (wid > 1) wb += wcnt[1];
        if (wid > 2) wb += wcnt[2];
        const int b0 = wb, b1 = b0 + p0, b2 = b1 + p1, b3 = b2 + p2;
        if (v.x == e) toklist[b0 + __popcll(m0 & lt)] = (unsigned short)(tb + 0);
        if (v.y == e) toklist[b1 + __popcll(m1 & lt)] = (unsigned short)(tb + 1);
        if (v.z == e) toklist[b2 + __popcll(m2 & lt)] = (unsigned short)(tb + 2);
        if (v.w == e) toklist[b3 + __popcll(m3 & lt)] = (unsigned short)(tb + 3);
        running += wcnt[0] + wcnt[1] + wcnt[2] + wcnt[3];
        __syncthreads();
    }
    const int ce = running;

    // ---- stage W panel -> bf16, transposed [col][k]; thread t handles k = t ----
    {
        const float* wr = w + (size_t)e * DIN * DOUT + (size_t)tid * DOUT + obase;
#pragma unroll
        for (int j = 0; j < 8; ++j) {
            const float4 v = *reinterpret_cast<const float4*>(wr + j * 4);
            wls[(j * 4 + 0) * XSTR + tid] = f2bf(v.x);
            wls[(j * 4 + 1) * XSTR + tid] = f2bf(v.y);
            wls[(j * 4 + 2) * XSTR + tid] = f2bf(v.z);
            wls[(j * 4 + 3) * XSTR + tid] = f2bf(v.w);
        }
    }
    __syncthreads();
    if (ce == 0) return;   // block-uniform

    // fragment lane roles (16x16x32 bf16):
    //   A: row = lane&15, k = (lane>>4)*8 + i   (contiguous 8 -> one b128)
    //   B: col = lane&15, k = (lane>>4)*8 + i
    //   C/D: col = lane&15, row = (lane>>4)*4 + reg   [m89-verified]
    const int a15 = lane & 15;
    const int kg  = lane >> 4;
    const float bv0 = bias[(size_t)e * DOUT + obase + a15];
    const float bv1 = bias[(size_t)e * DOUT + obase + 16 + a15];

    for (int t0 = half * CT; t0 < ce; t0 += 2 * CT) {
        // ---- gather 64 token rows -> bf16 -> xls[tok][k] ----
        {
            const int slot = tid & 63;            // token slot
            const int kq   = (tid >> 6) * 64;     // k-quarter per wave
            const int tok  = toklist[min(t0 + slot, ce - 1)];
            const float* xr = x + (size_t)tok * DIN + kq;
            unsigned short* dst = &xls[slot * XSTR + kq];
#pragma unroll
            for (int j = 0; j < 16; ++j) {
                const float4 v = *reinterpret_cast<const float4*>(xr + j * 4);
                uint2 p;
                p.x = (unsigned)f2bf(v.x) | ((unsigned)f2bf(v.y) << 16);
                p.y = (unsigned)f2bf(v.z) | ((unsigned)f2bf(v.w) << 16);
                *reinterpret_cast<uint2*>(dst + j * 4) = p;
            }
        }
        __syncthreads();

        // ---- MFMA k-loop: wave owns 16 tokens x 32 cols ----
        const unsigned short* ax  = &xls[(wid * 16 + a15) * XSTR];
        const unsigned short* bw0 = &wls[a15 * XSTR];
        const unsigned short* bw1 = &wls[(16 + a15) * XSTR];
        float4v acc0 = {0.f, 0.f, 0.f, 0.f};
        float4v acc1 = {0.f, 0.f, 0.f, 0.f};
#pragma unroll
        for (int kk = 0; kk < 8; ++kk) {
            const int kb = kk * 32 + kg * 8;
            const short8v a  = *reinterpret_cast<const short8v*>(ax + kb);
            const short8v b0 = *reinterpret_cast<const short8v*>(bw0 + kb);
            const short8v b1 = *reinterpret_cast<const short8v*>(bw1 + kb);
            acc0 = __builtin_amdgcn_mfma_f32_16x16x32_bf16(a, b0, acc0, 0, 0, 0);
            acc1 = __builtin_amdgcn_mfma_f32_16x16x32_bf16(a, b1, acc1, 0, 0, 0);
        }

        // ---- store: row = t0 + wid*16 + kg*4 + r ----
#pragma unroll
        for (int r = 0; r < 4; ++r) {
            const int sl = t0 + wid * 16 + kg * 4 + r;
            if (sl < ce) {
                const int row = toklist[sl];
                float* op = out + (size_t)row * DOUT + obase;
                op[a15]      = acc0[r] + bv0;
                op[16 + a15] = acc1[r] + bv1;
            }
        }
        __syncthreads();   // xls overwrite guard for next chunk
    }
}

extern "C" void kernel_launch(void* const* d_in, const int* in_sizes, int n_in,
                              void* d_out, int out_size, void* d_ws, size_t ws_size,
                              hipStream_t stream) {
    const float* x      = (const float*)d_in[0];
    const int*   index  = (const int*)d_in[1];
    const float* weight = (const float*)d_in[2];
    const float* bias   = (const float*)d_in[3];
    float* out = (float*)d_out;

    // 2 token-halves x 8 col-slices x 32 experts = 512 blocks = 2 per CU
    moe_mfma_kernel<<<2 * NE * 8, 256, 0, stream>>>(x, index, weight, bias, out);
}

// Round 12
// 15.135 us; speedup vs baseline: 60.0654x; 1.0546x over previous
//
#include <hip/hip_runtime.h>

#define NE    32
#define DIN   256
#define DOUT  256
#define TN    32     // output cols per block
#define SPL   4      // token-split factor
#define XSTR  264    // u16 stride (256 + 8 pad)

typedef __attribute__((ext_vector_type(8))) short short8v;   // 8 bf16 = 4 VGPR
typedef __attribute__((ext_vector_type(4))) float float4v;   // MFMA accumulator

__device__ __forceinline__ unsigned short f2bf(float f) {
    // fp32 -> bf16 round-to-nearest-even (inputs finite); verified R10 (absmax 0.031)
    unsigned u = __float_as_uint(f);
    return (unsigned short)((u + 0x7FFFu + ((u >> 16) & 1u)) >> 16);
}

// MFMA MoE v3: block = (split, expert, col-slice), grid 1024 = 4 blocks/CU.
// x is gathered DIRECTLY into registers as MFMA A-fragments (lane's frag = 8
// consecutive floats of one row -> 2 float4 global loads per k-step): no x-LDS,
// no per-chunk barriers -- the main loop is barrier-free and waves drift
// independently. LDS holds only the bf16-transposed W panel + u16 toklist (25 KB).
__global__ __launch_bounds__(256, 4) void moe_mfma_kernel(
    const float* __restrict__ x, const int* __restrict__ idx,
    const float* __restrict__ w, const float* __restrict__ bias,
    float* __restrict__ out)
{
    __shared__ unsigned short wls[TN * XSTR];   // 16896 B [col][k] bf16 (transposed)
    __shared__ unsigned short toklist[4096];    //  8192 B token ids
    __shared__ int wcnt[4][4];                  // [round][wave]

    const int tid   = threadIdx.x;
    const int e     = blockIdx.x & 31;          // expert; XCD = bx%8 = e%8
    const int cb    = (blockIdx.x >> 5) & 7;    // col slice
    const int s     = blockIdx.x >> 8;          // token split 0..3
    const int obase = cb * TN;
    const int lane  = tid & 63;
    const int wid   = tid >> 6;
    const unsigned long long lt = (1ull << lane) - 1ull;

    // ---- load all indices up front (4 int4/thread) ----
    int4 v0 = *reinterpret_cast<const int4*>(idx + 0 * 1024 + tid * 4);
    int4 v1 = *reinterpret_cast<const int4*>(idx + 1 * 1024 + tid * 4);
    int4 v2 = *reinterpret_cast<const int4*>(idx + 2 * 1024 + tid * 4);
    int4 v3 = *reinterpret_cast<const int4*>(idx + 3 * 1024 + tid * 4);

    // ---- collect: deterministic ballot-scan, 1 barrier/round (wcnt slots per
    // round never alias across the barrier) ----
    int running = 0;
#define ROUND(vv, r)                                                                   \
    {                                                                                  \
        const int tb = (r) * 1024 + tid * 4;                                           \
        const unsigned long long m0 = __ballot((vv).x == e);                           \
        const unsigned long long m1 = __ballot((vv).y == e);                           \
        const unsigned long long m2 = __ballot((vv).z == e);                           \
        const unsigned long long m3 = __ballot((vv).w == e);                           \
        const int p0 = __popcll(m0), p1 = __popcll(m1), p2 = __popcll(m2), p3 = __popcll(m3); \
        if (lane == 0) wcnt[r][wid] = p0 + p1 + p2 + p3;                               \
        __syncthreads();                                                               \
        int wb = running;                                                              \
        if (wid > 0) wb += wcnt[r][0];                                                 \
        if (wid > 1) wb += wcnt[r][1];                                                 \
        if (wid > 2) wb += wcnt[r][2];                                                 \
        const int b0 = wb, b1 = b0 + p0, b2 = b1 + p1, b3 = b2 + p2;                   \
        if ((vv).x == e) toklist[b0 + __popcll(m0 & lt)] = (unsigned short)(tb + 0);   \
        if ((vv).y == e) toklist[b1 + __popcll(m1 & lt)] = (unsigned short)(tb + 1);   \
        if ((vv).z == e) toklist[b2 + __popcll(m2 & lt)] = (unsigned short)(tb + 2);   \
        if ((vv).w == e) toklist[b3 + __popcll(m3 & lt)] = (unsigned short)(tb + 3);   \
        running += wcnt[r][0] + wcnt[r][1] + wcnt[r][2] + wcnt[r][3];                  \
    }
    ROUND(v0, 0) ROUND(v1, 1) ROUND(v2, 2) ROUND(v3, 3)
#undef ROUND
    const int ce = running;
    if (ce <= s * (4 * 16)) return;   // this split has no tokens (block-uniform)

    // ---- stage W panel -> bf16, transposed [col][k]; thread t handles k = t ----
    {
        const float* wr = w + (size_t)e * DIN * DOUT + (size_t)tid * DOUT + obase;
#pragma unroll
        for (int j = 0; j < 8; ++j) {
            const float4 q = *reinterpret_cast<const float4*>(wr + j * 4);
            wls[(j * 4 + 0) * XSTR + tid] = f2bf(q.x);
            wls[(j * 4 + 1) * XSTR + tid] = f2bf(q.y);
            wls[(j * 4 + 2) * XSTR + tid] = f2bf(q.z);
            wls[(j * 4 + 3) * XSTR + tid] = f2bf(q.w);
        }
    }
    __syncthreads();   // covers last collect round's toklist writes + W stage

    // fragment lane roles (16x16x32 bf16):
    //   A: row = lane&15, k = (lane>>4)*8 + i  (8 consecutive -> 2 float4 from global)
    //   B: col = lane&15, k = (lane>>4)*8 + i  (b128 from wls)
    //   C/D: col = lane&15, row = (lane>>4)*4 + reg
    const int a15 = lane & 15;
    const int kg  = lane >> 4;
    const float bv0 = bias[(size_t)e * DOUT + obase + a15];
    const float bv1 = bias[(size_t)e * DOUT + obase + 16 + a15];
    const unsigned short* bw0 = &wls[a15 * XSTR];
    const unsigned short* bw1 = &wls[(16 + a15) * XSTR];

    // ---- barrier-free main loop: each wave owns token group (s*4+wid), stride 16 groups ----
    for (int tb0 = (s * 4 + wid) * 16; tb0 < ce; tb0 += SPL * 4 * 16) {
        const int tok = toklist[min(tb0 + a15, ce - 1)];
        const float* xr = x + (size_t)tok * DIN + kg * 8;

        float4 L[16];   // 16 independent dwordx4 -> one latency exposure
#pragma unroll
        for (int kk = 0; kk < 8; ++kk) {
            L[2 * kk]     = *reinterpret_cast<const float4*>(xr + kk * 32);
            L[2 * kk + 1] = *reinterpret_cast<const float4*>(xr + kk * 32 + 4);
        }

        float4v acc0 = {0.f, 0.f, 0.f, 0.f};
        float4v acc1 = {0.f, 0.f, 0.f, 0.f};
#pragma unroll
        for (int kk = 0; kk < 8; ++kk) {
            const float4 u0 = L[2 * kk], u1 = L[2 * kk + 1];
            short8v a;
            a[0] = (short)f2bf(u0.x); a[1] = (short)f2bf(u0.y);
            a[2] = (short)f2bf(u0.z); a[3] = (short)f2bf(u0.w);
            a[4] = (short)f2bf(u1.x); a[5] = (short)f2bf(u1.y);
            a[6] = (short)f2bf(u1.z); a[7] = (short)f2bf(u1.w);
            const int kb = kk * 32 + kg * 8;
            const short8v b0 = *reinterpret_cast<const short8v*>(bw0 + kb);
            const short8v b1 = *reinterpret_cast<const short8v*>(bw1 + kb);
            acc0 = __builtin_amdgcn_mfma_f32_16x16x32_bf16(a, b0, acc0, 0, 0, 0);
            acc1 = __builtin_amdgcn_mfma_f32_16x16x32_bf16(a, b1, acc1, 0, 0, 0);
        }

#pragma unroll
        for (int r = 0; r < 4; ++r) {
            const int sl = tb0 + kg * 4 + r;
            if (sl < ce) {
                const int row = toklist[sl];
                float* op = out + (size_t)row * DOUT + obase;
                op[a15]      = acc0[r] + bv0;
                op[16 + a15] = acc1[r] + bv1;
            }
        }
    }
}

extern "C" void kernel_launch(void* const* d_in, const int* in_sizes, int n_in,
                              void* d_out, int out_size, void* d_ws, size_t ws_size,
                              hipStream_t stream) {
    const float* x      = (const float*)d_in[0];
    const int*   index  = (const int*)d_in[1];
    const float* weight = (const float*)d_in[2];
    const float* bias   = (const float*)d_in[3];
    float* out = (float*)d_out;

    // 4 splits x 8 col-slices x 32 experts = 1024 blocks = 4/CU; bx%8 = e%8 (XCD)
    moe_mfma_kernel<<<SPL * 8 * NE, 256, 0, stream>>>(x, index, weight, bias, out);
}